// Round 4
// baseline (110.445 us; speedup 1.0000x reference)
//
#include <hip/hip_runtime.h>
#include <math.h>

// TurboQuantValue: sign-flip -> FWHT128 -> 4-bit quant/dequant -> FWHT128 -> sign-flip.
// Layout: 4 lanes per row, 32 elems per lane, 16 rows per wave64.
// reg a[4k+i] holds element e = 16k + 4j + i  (j = lane&3, k = 0..7).
// In-register FWHT covers e-bits {0,1,4,5,6}; e-bits {2,3} are lane bits {0,1},
// done via quad_perm DPP (VALU pipe) -> ZERO LDS/DS instructions.
// All 1/sqrt(128) normalizations folded into per-row scalars.

#define DIM 128
#define INV_SQRT_DIM 0.08838834764831845f

// lane XOR within quads via DPP quad_perm (full-rate VALU, no LDS pipe)
__device__ __forceinline__ float dpp_xor1(float v) {  // quad_perm [1,0,3,2]
    return __int_as_float(__builtin_amdgcn_mov_dpp(__float_as_int(v), 0xB1, 0xF, 0xF, false));
}
__device__ __forceinline__ float dpp_xor2(float v) {  // quad_perm [2,3,0,1]
    return __int_as_float(__builtin_amdgcn_mov_dpp(__float_as_int(v), 0x4E, 0xF, 0xF, false));
}

__device__ __forceinline__ float sflip(float v, unsigned sbits, int k) {
    unsigned m = ((sbits >> k) & 1u) << 31;
    return __int_as_float(__float_as_int(v) ^ m);
}

// raw (unnormalized) FWHT over 128 elems: 5 in-register stages + 2 DPP stages
__device__ __forceinline__ void fwht_raw(float a[32], int lane) {
#pragma unroll
    for (int h = 1; h < 32; h <<= 1) {
#pragma unroll
        for (int i = 0; i < 32; ++i) {
            if (!(i & h)) {
                float u = a[i], w = a[i + h];
                a[i] = u + w;
                a[i + h] = u - w;
            }
        }
    }
    {
        const float sgn = (lane & 1) ? -1.0f : 1.0f;
#pragma unroll
        for (int i = 0; i < 32; ++i) { float b = dpp_xor1(a[i]); a[i] = fmaf(sgn, a[i], b); }
    }
    {
        const float sgn = (lane & 2) ? -1.0f : 1.0f;
#pragma unroll
        for (int i = 0; i < 32; ++i) { float b = dpp_xor2(a[i]); a[i] = fmaf(sgn, a[i], b); }
    }
}

__global__ __launch_bounds__(256) void turboquant_kernel(
    const float* __restrict__ x, const float* __restrict__ signs,
    float* __restrict__ out, long long nrows) {
    const int lane = threadIdx.x & 63;
    const int j    = lane & 3;   // lane within row; owns elems 16k + 4j + i
    const int rsub = lane >> 2;  // row within the wave's 16-row group

    // per-lane sign bitmask (1 = negative); bit (4k+i) <-> signs[16k + 4j + i]
    unsigned sbits = 0;
#pragma unroll
    for (int k = 0; k < 8; ++k) {
        float4 sv = *reinterpret_cast<const float4*>(signs + k * 16 + j * 4);
        if (sv.x < 0.5f) sbits |= 1u << (k * 4 + 0);
        if (sv.y < 0.5f) sbits |= 1u << (k * 4 + 1);
        if (sv.z < 0.5f) sbits |= 1u << (k * 4 + 2);
        if (sv.w < 0.5f) sbits |= 1u << (k * 4 + 3);
    }

    const long long waves_total = (long long)gridDim.x * 4;
    const long long wid = (long long)blockIdx.x * 4 + (threadIdx.x >> 6);

    for (long long it = wid; it * 16 < nrows; it += waves_total) {
        const long long row = it * 16 + rsub;
        if (row >= nrows) continue;
        const float* rp = x + row * DIM + j * 4;

        float a[32];
#pragma unroll
        for (int k = 0; k < 8; ++k) {
            float4 v = *reinterpret_cast<const float4*>(rp + k * 16);
            a[k * 4 + 0] = sflip(v.x, sbits, k * 4 + 0);
            a[k * 4 + 1] = sflip(v.y, sbits, k * 4 + 1);
            a[k * 4 + 2] = sflip(v.z, sbits, k * 4 + 2);
            a[k * 4 + 3] = sflip(v.w, sbits, k * 4 + 3);
        }

        fwht_raw(a, lane);  // a = R = raw H(s*x); true r = R/sqrt(128)

        // fused reductions over the row's 4 lanes: ss = sum R^2, sa = sum |R|
        float ss = 0.0f, sa = 0.0f;
#pragma unroll
        for (int i = 0; i < 32; ++i) {
            ss = fmaf(a[i], a[i], ss);
            sa += fabsf(a[i]);
        }
        ss += dpp_xor1(ss); sa += dpp_xor1(sa);
        ss += dpp_xor2(ss); sa += dpp_xor2(sa);

        const float norm   = sqrtf(ss) * INV_SQRT_DIM;   // |r|
        const float t      = norm + 1e-8f;               // norm + EPS
        const float scales = (0.456f / 128.0f) * sa / t; // C * mean|u|
        const float sden   = scales + 1e-8f;
        const float id     = 1.0f / (t * sden);          // u/sden == R * id
        const float ofac   = scales * norm * (1.0f / 128.0f);

        // q = clip(round(u/sden), -8, 7)   (pack/unpack is identity)
#pragma unroll
        for (int i = 0; i < 32; ++i)
            a[i] = fminf(fmaxf(rintf(a[i] * id), -8.0f), 7.0f);

        fwht_raw(a, lane);  // raw inverse; normalization folded into ofac

        float* op = out + row * DIM + j * 4;
#pragma unroll
        for (int k = 0; k < 8; ++k) {
            float4 o;
            o.x = sflip(a[k * 4 + 0] * ofac, sbits, k * 4 + 0);
            o.y = sflip(a[k * 4 + 1] * ofac, sbits, k * 4 + 1);
            o.z = sflip(a[k * 4 + 2] * ofac, sbits, k * 4 + 2);
            o.w = sflip(a[k * 4 + 3] * ofac, sbits, k * 4 + 3);
            *reinterpret_cast<float4*>(op + k * 16) = o;
        }
    }
}

extern "C" void kernel_launch(void* const* d_in, const int* in_sizes, int n_in,
                              void* d_out, int out_size, void* d_ws, size_t ws_size,
                              hipStream_t stream) {
    const float* x     = (const float*)d_in[0];
    const float* signs = (const float*)d_in[1];
    float* out = (float*)d_out;
    const long long nrows = (long long)in_sizes[0] / DIM;
    turboquant_kernel<<<2048, 256, 0, stream>>>(x, signs, out, nrows);
}

// Round 5
// 102.989 us; speedup vs baseline: 1.0724x; 1.0724x over previous
//
#include <hip/hip_runtime.h>
#include <math.h>

// TurboQuantValue: sign-flip -> FWHT128 -> 4-bit quant/dequant -> FWHT128 -> sign-flip.
// Layout: 8 lanes per row, 16 elems per lane (permuted for coalescing):
// reg a[4k+i] holds element e = 32k + 4j + i (j = lane&7). Cross-lane FWHT
// stages: lane-xor1/xor2 via quad_perm DPP (VALU pipe), lane-xor4 via
// ds_swizzle. 2-deep software pipeline: tile n+1's global loads issue before
// tile n's compute, so HBM latency hides under the ~300-op serial chain.

#define DIM 128
#define INV_SQRT_DIM 0.08838834764831845f

__device__ __forceinline__ float dpp_xor1(float v) {  // quad_perm [1,0,3,2]
    return __int_as_float(__builtin_amdgcn_mov_dpp(__float_as_int(v), 0xB1, 0xF, 0xF, false));
}
__device__ __forceinline__ float dpp_xor2(float v) {  // quad_perm [2,3,0,1]
    return __int_as_float(__builtin_amdgcn_mov_dpp(__float_as_int(v), 0x4E, 0xF, 0xF, false));
}
__device__ __forceinline__ float swz_xor4(float v) {  // BitMode ds_swizzle lane^4
    int r = __builtin_amdgcn_ds_swizzle(__float_as_int(v), (4 << 10) | 0x1F);
    return __int_as_float(r);
}

__device__ __forceinline__ float sflip(float v, unsigned sbits, int k) {
    unsigned m = ((sbits >> k) & 1u) << 31;
    return __int_as_float(__float_as_int(v) ^ m);
}

// raw (unnormalized) FWHT over 128 elems; reg bits = e-bits {0,1,5,6},
// lane bits 0-2 = e-bits {2,3,4}. Butterfly stage order is arbitrary.
__device__ __forceinline__ void fwht_raw(float a[16], int lane) {
#pragma unroll
    for (int h = 1; h < 16; h <<= 1) {
#pragma unroll
        for (int i = 0; i < 16; ++i) {
            if (!(i & h)) {
                float u = a[i], w = a[i + h];
                a[i] = u + w;
                a[i + h] = u - w;
            }
        }
    }
    {
        const float sgn = (lane & 1) ? -1.0f : 1.0f;
#pragma unroll
        for (int i = 0; i < 16; ++i) { float b = dpp_xor1(a[i]); a[i] = fmaf(sgn, a[i], b); }
    }
    {
        const float sgn = (lane & 2) ? -1.0f : 1.0f;
#pragma unroll
        for (int i = 0; i < 16; ++i) { float b = dpp_xor2(a[i]); a[i] = fmaf(sgn, a[i], b); }
    }
    {
        const float sgn = (lane & 4) ? -1.0f : 1.0f;
#pragma unroll
        for (int i = 0; i < 16; ++i) { float b = swz_xor4(a[i]); a[i] = fmaf(sgn, a[i], b); }
    }
}

__global__ __launch_bounds__(256) void turboquant_kernel(
    const float* __restrict__ x, const float* __restrict__ signs,
    float* __restrict__ out, long long nrows) {
    const int lane = threadIdx.x & 63;
    const int j    = lane & 7;   // lane within row
    const int rsub = lane >> 3;  // row within the wave's 8-row tile

    // per-lane sign bitmask (1 = negative); bit (4k+i) <-> signs[32k + 4j + i]
    unsigned sbits = 0;
#pragma unroll
    for (int k = 0; k < 4; ++k) {
        float4 sv = *reinterpret_cast<const float4*>(signs + k * 32 + j * 4);
        if (sv.x < 0.5f) sbits |= 1u << (k * 4 + 0);
        if (sv.y < 0.5f) sbits |= 1u << (k * 4 + 1);
        if (sv.z < 0.5f) sbits |= 1u << (k * 4 + 2);
        if (sv.w < 0.5f) sbits |= 1u << (k * 4 + 3);
    }

    const long long ntiles = nrows >> 3;  // 8 rows per tile
    const long long waves_total = (long long)gridDim.x * 4;
    long long t = (long long)blockIdx.x * 4 + (threadIdx.x >> 6);

    const long long lofs = (long long)rsub * DIM + j * 4;  // lane's base within a tile

    float4 cur[4];
    if (t < ntiles) {
        const float* rp = x + t * (8 * DIM) + lofs;
#pragma unroll
        for (int k = 0; k < 4; ++k) cur[k] = *reinterpret_cast<const float4*>(rp + k * 32);
    }

    while (t < ntiles) {
        // ---- prefetch tile t+waves_total (loads issue now, waited on at loop end)
        const long long tn = t + waves_total;
        float4 nxt[4] = {};
        if (tn < ntiles) {
            const float* rp = x + tn * (8 * DIM) + lofs;
#pragma unroll
            for (int k = 0; k < 4; ++k) nxt[k] = *reinterpret_cast<const float4*>(rp + k * 32);
        }

        // ---- compute on cur
        float a[16];
#pragma unroll
        for (int k = 0; k < 4; ++k) {
            a[k * 4 + 0] = sflip(cur[k].x, sbits, k * 4 + 0);
            a[k * 4 + 1] = sflip(cur[k].y, sbits, k * 4 + 1);
            a[k * 4 + 2] = sflip(cur[k].z, sbits, k * 4 + 2);
            a[k * 4 + 3] = sflip(cur[k].w, sbits, k * 4 + 3);
        }

        fwht_raw(a, lane);  // a = R = raw H(s*x); true r = R/sqrt(128)

        float ss = 0.0f, sa = 0.0f;
#pragma unroll
        for (int i = 0; i < 16; ++i) {
            ss = fmaf(a[i], a[i], ss);
            sa += fabsf(a[i]);
        }
        ss += dpp_xor1(ss); sa += dpp_xor1(sa);
        ss += dpp_xor2(ss); sa += dpp_xor2(sa);
        ss += swz_xor4(ss); sa += swz_xor4(sa);

        const float norm   = sqrtf(ss) * INV_SQRT_DIM;   // |r|
        const float tt     = norm + 1e-8f;               // norm + EPS
        const float scales = (0.456f / 128.0f) * sa / tt;
        const float sden   = scales + 1e-8f;
        const float id     = 1.0f / (tt * sden);         // u/sden == R * id
        const float ofac   = scales * norm * (1.0f / 128.0f);

#pragma unroll
        for (int i = 0; i < 16; ++i)
            a[i] = fminf(fmaxf(rintf(a[i] * id), -8.0f), 7.0f);

        fwht_raw(a, lane);  // raw inverse; normalization folded into ofac

        float* op = out + t * (8 * DIM) + lofs;
#pragma unroll
        for (int k = 0; k < 4; ++k) {
            float4 o;
            o.x = sflip(a[k * 4 + 0] * ofac, sbits, k * 4 + 0);
            o.y = sflip(a[k * 4 + 1] * ofac, sbits, k * 4 + 1);
            o.z = sflip(a[k * 4 + 2] * ofac, sbits, k * 4 + 2);
            o.w = sflip(a[k * 4 + 3] * ofac, sbits, k * 4 + 3);
            *reinterpret_cast<float4*>(op + k * 32) = o;
        }

        // ---- rotate pipeline
        t = tn;
#pragma unroll
        for (int k = 0; k < 4; ++k) cur[k] = nxt[k];
    }
}

extern "C" void kernel_launch(void* const* d_in, const int* in_sizes, int n_in,
                              void* d_out, int out_size, void* d_ws, size_t ws_size,
                              hipStream_t stream) {
    const float* x     = (const float*)d_in[0];
    const float* signs = (const float*)d_in[1];
    float* out = (float*)d_out;
    const long long nrows = (long long)in_sizes[0] / DIM;
    turboquant_kernel<<<2048, 256, 0, stream>>>(x, signs, out, nrows);
}

// Round 7
// 86.170 us; speedup vs baseline: 1.2817x; 1.1952x over previous
//
#include <hip/hip_runtime.h>
#include <math.h>

// TurboQuantValue: sign-flip -> FWHT128 -> 4-bit quant/dequant -> FWHT128 -> sign-flip.
// Layout: 8 lanes per row, 16 elems per lane (permuted for coalescing):
// reg a[4k+i] holds element e = 32k + 4j + i (j = lane&7). Cross-lane FWHT
// stages: lane-xor1/xor2 via quad_perm DPP (VALU pipe), lane-xor4 via
// ds_swizzle. 2-deep software pipeline + NON-TEMPORAL output stores so the
// 268 MB write stream doesn't evict the (L3-resident, 268 MB) input.

#define DIM 128
#define INV_SQRT_DIM 0.08838834764831845f

typedef float floatx4 __attribute__((ext_vector_type(4)));  // native vec for nt-store

__device__ __forceinline__ float dpp_xor1(float v) {  // quad_perm [1,0,3,2]
    return __int_as_float(__builtin_amdgcn_mov_dpp(__float_as_int(v), 0xB1, 0xF, 0xF, false));
}
__device__ __forceinline__ float dpp_xor2(float v) {  // quad_perm [2,3,0,1]
    return __int_as_float(__builtin_amdgcn_mov_dpp(__float_as_int(v), 0x4E, 0xF, 0xF, false));
}
__device__ __forceinline__ float swz_xor4(float v) {  // BitMode ds_swizzle lane^4
    int r = __builtin_amdgcn_ds_swizzle(__float_as_int(v), (4 << 10) | 0x1F);
    return __int_as_float(r);
}

__device__ __forceinline__ float sflip(float v, unsigned sbits, int k) {
    unsigned m = ((sbits >> k) & 1u) << 31;
    return __int_as_float(__float_as_int(v) ^ m);
}

// raw (unnormalized) FWHT over 128 elems; reg bits = e-bits {0,1,5,6},
// lane bits 0-2 = e-bits {2,3,4}. Butterfly stage order is arbitrary.
__device__ __forceinline__ void fwht_raw(float a[16], int lane) {
#pragma unroll
    for (int h = 1; h < 16; h <<= 1) {
#pragma unroll
        for (int i = 0; i < 16; ++i) {
            if (!(i & h)) {
                float u = a[i], w = a[i + h];
                a[i] = u + w;
                a[i + h] = u - w;
            }
        }
    }
    {
        const float sgn = (lane & 1) ? -1.0f : 1.0f;
#pragma unroll
        for (int i = 0; i < 16; ++i) { float b = dpp_xor1(a[i]); a[i] = fmaf(sgn, a[i], b); }
    }
    {
        const float sgn = (lane & 2) ? -1.0f : 1.0f;
#pragma unroll
        for (int i = 0; i < 16; ++i) { float b = dpp_xor2(a[i]); a[i] = fmaf(sgn, a[i], b); }
    }
    {
        const float sgn = (lane & 4) ? -1.0f : 1.0f;
#pragma unroll
        for (int i = 0; i < 16; ++i) { float b = swz_xor4(a[i]); a[i] = fmaf(sgn, a[i], b); }
    }
}

__global__ __launch_bounds__(256) void turboquant_kernel(
    const float* __restrict__ x, const float* __restrict__ signs,
    float* __restrict__ out, long long nrows) {
    const int lane = threadIdx.x & 63;
    const int j    = lane & 7;   // lane within row
    const int rsub = lane >> 3;  // row within the wave's 8-row tile

    // per-lane sign bitmask (1 = negative); bit (4k+i) <-> signs[32k + 4j + i]
    unsigned sbits = 0;
#pragma unroll
    for (int k = 0; k < 4; ++k) {
        float4 sv = *reinterpret_cast<const float4*>(signs + k * 32 + j * 4);
        if (sv.x < 0.5f) sbits |= 1u << (k * 4 + 0);
        if (sv.y < 0.5f) sbits |= 1u << (k * 4 + 1);
        if (sv.z < 0.5f) sbits |= 1u << (k * 4 + 2);
        if (sv.w < 0.5f) sbits |= 1u << (k * 4 + 3);
    }

    const long long ntiles = nrows >> 3;  // 8 rows per tile
    const long long waves_total = (long long)gridDim.x * 4;
    long long t = (long long)blockIdx.x * 4 + (threadIdx.x >> 6);

    const long long lofs = (long long)rsub * DIM + j * 4;  // lane's base within a tile

    float4 cur[4];
    if (t < ntiles) {
        const float* rp = x + t * (8 * DIM) + lofs;
#pragma unroll
        for (int k = 0; k < 4; ++k) cur[k] = *reinterpret_cast<const float4*>(rp + k * 32);
    }

    while (t < ntiles) {
        // ---- prefetch tile t+waves_total (loads issue now, waited on at loop end)
        const long long tn = t + waves_total;
        float4 nxt[4] = {};
        if (tn < ntiles) {
            const float* rp = x + tn * (8 * DIM) + lofs;
#pragma unroll
            for (int k = 0; k < 4; ++k) nxt[k] = *reinterpret_cast<const float4*>(rp + k * 32);
        }

        // ---- compute on cur
        float a[16];
#pragma unroll
        for (int k = 0; k < 4; ++k) {
            a[k * 4 + 0] = sflip(cur[k].x, sbits, k * 4 + 0);
            a[k * 4 + 1] = sflip(cur[k].y, sbits, k * 4 + 1);
            a[k * 4 + 2] = sflip(cur[k].z, sbits, k * 4 + 2);
            a[k * 4 + 3] = sflip(cur[k].w, sbits, k * 4 + 3);
        }

        fwht_raw(a, lane);  // a = R = raw H(s*x); true r = R/sqrt(128)

        float ss = 0.0f, sa = 0.0f;
#pragma unroll
        for (int i = 0; i < 16; ++i) {
            ss = fmaf(a[i], a[i], ss);
            sa += fabsf(a[i]);
        }
        ss += dpp_xor1(ss); sa += dpp_xor1(sa);
        ss += dpp_xor2(ss); sa += dpp_xor2(sa);
        ss += swz_xor4(ss); sa += swz_xor4(sa);

        const float norm   = sqrtf(ss) * INV_SQRT_DIM;   // |r|
        const float tt     = norm + 1e-8f;               // norm + EPS
        const float scales = (0.456f / 128.0f) * sa / tt;
        const float sden   = scales + 1e-8f;
        const float id     = 1.0f / (tt * sden);         // u/sden == R * id
        const float ofac   = scales * norm * (1.0f / 128.0f);

#pragma unroll
        for (int i = 0; i < 16; ++i)
            a[i] = fminf(fmaxf(rintf(a[i] * id), -8.0f), 7.0f);

        fwht_raw(a, lane);  // raw inverse; normalization folded into ofac

        float* op = out + t * (8 * DIM) + lofs;
#pragma unroll
        for (int k = 0; k < 4; ++k) {
            floatx4 o;
            o.x = sflip(a[k * 4 + 0] * ofac, sbits, k * 4 + 0);
            o.y = sflip(a[k * 4 + 1] * ofac, sbits, k * 4 + 1);
            o.z = sflip(a[k * 4 + 2] * ofac, sbits, k * 4 + 2);
            o.w = sflip(a[k * 4 + 3] * ofac, sbits, k * 4 + 3);
            // non-temporal: don't let the write stream evict the L3-resident input
            __builtin_nontemporal_store(o, reinterpret_cast<floatx4*>(op + k * 32));
        }

        // ---- rotate pipeline
        t = tn;
#pragma unroll
        for (int k = 0; k < 4; ++k) cur[k] = nxt[k];
    }
}

extern "C" void kernel_launch(void* const* d_in, const int* in_sizes, int n_in,
                              void* d_out, int out_size, void* d_ws, size_t ws_size,
                              hipStream_t stream) {
    const float* x     = (const float*)d_in[0];
    const float* signs = (const float*)d_in[1];
    float* out = (float*)d_out;
    const long long nrows = (long long)in_sizes[0] / DIM;
    turboquant_kernel<<<2048, 256, 0, stream>>>(x, signs, out, nrows);
}